// Round 6
// baseline (634.651 us; speedup 1.0000x reference)
//
#include <hip/hip_runtime.h>
#include <hip/hip_bf16.h>

#define BB 8
#define NN 2048
#define FD 128

typedef float f32x4 __attribute__((ext_vector_type(4)));
typedef short bf16x8 __attribute__((ext_vector_type(8)));
typedef short s16x4 __attribute__((ext_vector_type(4)));

__device__ __forceinline__ short f2bf(float f) {
  union { __hip_bfloat16 h; short s; } u;
  u.h = __float2bfloat16(f);
  return u.s;
}

// ---------------- kernel 1: r = rsqrt(1 + rowsum(adj)) ----------------
// DIAGNOSTIC: body repeated 4x (idempotent) so the dispatch exceeds the
// 76us poison-fills and appears in the top-5 rocprof rows. Real dur = /4.
__global__ __launch_bounds__(256) void k_degree_x4(const float* __restrict__ adj,
                                                   float* __restrict__ r) {
  const int row  = blockIdx.x * 4 + (threadIdx.x >> 6);
  const int lane = threadIdx.x & 63;
#pragma unroll 1
  for (int rep = 0; rep < 4; ++rep) {
    const f32x4* p = reinterpret_cast<const f32x4*>(adj + (size_t)row * NN);
    float s = 0.f;
#pragma unroll
    for (int i = 0; i < 8; ++i) {
      f32x4 v = p[lane + 64 * i];
      s += (v.x + v.y) + (v.z + v.w);
    }
#pragma unroll
    for (int off = 32; off >= 1; off >>= 1) s += __shfl_xor(s, off, 64);
    if (lane == 0) r[row] = rsqrtf(1.0f + s);
    asm volatile("" ::: "memory");
  }
}

// ---------------- kernel 2: XWs = r[m] * (X @ W), pack B-fragments ----------
// bpack: elem (m,o) -> (m>>3)*1024 + o*8 + (m&7); xwsr fp32 row-major.
__global__ __launch_bounds__(256) void k_xw(const float* __restrict__ X,
                                            const float* __restrict__ W,
                                            const float* __restrict__ r,
                                            short* __restrict__ bpack,
                                            float* __restrict__ xwsr) {
  __shared__ __align__(16) float Xs[64][132];
  __shared__ __align__(16) float Ws[128][128];
  const int b  = blockIdx.y;
  const int m0 = blockIdx.x * 64;
  const int t  = threadIdx.x;
  {
    const f32x4* wp = reinterpret_cast<const f32x4*>(W);
    f32x4* wd = reinterpret_cast<f32x4*>(&Ws[0][0]);
#pragma unroll
    for (int i = 0; i < 16; ++i) wd[t + 256 * i] = wp[t + 256 * i];
    const f32x4* xp = reinterpret_cast<const f32x4*>(X + ((size_t)b * NN + m0) * FD);
#pragma unroll
    for (int i = 0; i < 8; ++i) {
      int slot = t + 256 * i;
      f32x4 v = xp[slot];
      *reinterpret_cast<f32x4*>(&Xs[slot >> 5][(slot & 31) * 4]) = v;
    }
  }
  __syncthreads();
  const int ot = (t & 15) * 8;
  const int mt = (t >> 4) * 4;
  float acc[4][8];
#pragma unroll
  for (int i = 0; i < 4; ++i)
#pragma unroll
    for (int j = 0; j < 8; ++j) acc[i][j] = 0.f;

  for (int k = 0; k < 128; k += 4) {
    f32x4 xv[4];
#pragma unroll
    for (int i = 0; i < 4; ++i) xv[i] = *reinterpret_cast<const f32x4*>(&Xs[mt + i][k]);
#pragma unroll
    for (int kk = 0; kk < 4; ++kk) {
      float wv[8];
#pragma unroll
      for (int j = 0; j < 8; ++j) wv[j] = Ws[k + kk][ot + j];
#pragma unroll
      for (int i = 0; i < 4; ++i)
#pragma unroll
        for (int j = 0; j < 8; ++j) acc[i][j] = fmaf(xv[i][kk], wv[j], acc[i][j]);
    }
  }
  const int bm = b * NN + m0 + mt;
#pragma unroll
  for (int i = 0; i < 4; ++i) {
    float rm = r[bm + i];
#pragma unroll
    for (int j = 0; j < 8; ++j) acc[i][j] *= rm;
  }
#pragma unroll
  for (int i = 0; i < 4; ++i) {
    f32x4 lo = {acc[i][0], acc[i][1], acc[i][2], acc[i][3]};
    f32x4 hi = {acc[i][4], acc[i][5], acc[i][6], acc[i][7]};
    float* dst = xwsr + (size_t)(bm + i) * FD + ot;
    *reinterpret_cast<f32x4*>(dst) = lo;
    *reinterpret_cast<f32x4*>(dst + 4) = hi;
  }
  short* bp = bpack + (size_t)b * NN * FD;
  const int grp = (m0 + mt) >> 3;
  const int h   = ((m0 + mt) >> 2) & 1;
#pragma unroll
  for (int j = 0; j < 8; ++j) {
    s16x4 sv;
#pragma unroll
    for (int i = 0; i < 4; ++i) sv[i] = f2bf(acc[i][j]);
    *reinterpret_cast<s16x4*>(bp + (size_t)grp * 1024 + (ot + j) * 8 + h * 4) = sv;
  }
}

// ---------------- kernel 3: LDS-free MFMA GEMM, K-split waves ----------------
// DIAGNOSTIC: body repeated 3x (idempotent). Real dur = /3.
__global__ __launch_bounds__(256) void k_gemm2_x3(const float* __restrict__ adj,
                                                  const short* __restrict__ bpack,
                                                  const float* __restrict__ xwsr,
                                                  const float* __restrict__ r,
                                                  const float* __restrict__ bias,
                                                  float* __restrict__ out) {
  __shared__ float Red[2][16][132];
  const int b     = blockIdx.y;
  const int n0    = blockIdx.x * 32;
  const int t     = threadIdx.x;
  const int lane  = t & 63;
  const int w     = t >> 6;
  const int strip = w & 1;
  const int khalf = w >> 1;
  const int rowb  = n0 + strip * 16;

  const float* ap  = adj + ((size_t)b * NN + rowb + (lane & 15)) * NN + khalf * 1024 + (lane >> 4) * 8;
  const short* bpb = bpack + (size_t)b * NN * FD + (size_t)(khalf * 128 + (lane >> 4)) * 1024 + (lane & 15) * 8;

  auto loadA = [&](int ks, f32x4 (&d)[2]) {
    const f32x4* q = reinterpret_cast<const f32x4*>(ap + ks * 32);
    d[0] = q[0];
    d[1] = q[1];
  };

#pragma unroll 1
  for (int rep = 0; rep < 3; ++rep) {
    f32x4 acc[8];
#pragma unroll
    for (int i = 0; i < 8; ++i) acc[i] = (f32x4){0.f, 0.f, 0.f, 0.f};

    f32x4 aS[4][2];
    bf16x8 bS[2][8];

    auto loadB = [&](int ks, bf16x8 (&d)[8]) {
      const short* p = bpb + (size_t)ks * 4096;
#pragma unroll
      for (int ct = 0; ct < 8; ++ct)
        d[ct] = *reinterpret_cast<const bf16x8*>(p + ct * 128);
    };
    auto step = [&](f32x4 (&sa)[2], bf16x8 (&sb)[8]) {
      bf16x8 af;
#pragma unroll
      for (int i = 0; i < 4; ++i) { af[i] = f2bf(sa[0][i]); af[4 + i] = f2bf(sa[1][i]); }
      __builtin_amdgcn_s_setprio(1);
#pragma unroll
      for (int ct = 0; ct < 8; ++ct)
        acc[ct] = __builtin_amdgcn_mfma_f32_16x16x32_bf16(af, sb[ct], acc[ct], 0, 0, 0);
      __builtin_amdgcn_s_setprio(0);
    };

    loadA(0, aS[0]); loadA(1, aS[1]); loadA(2, aS[2]); loadA(3, aS[3]);
    loadB(0, bS[0]); loadB(1, bS[1]);
#pragma unroll
    for (int ks = 0; ks < 32; ++ks) {
      step(aS[ks & 3], bS[ks & 1]);
      if (ks + 4 < 32) loadA(ks + 4, aS[ks & 3]);
      if (ks + 2 < 32) loadB(ks + 2, bS[ks & 1]);
    }

    // ---- cross-wave K reduction + fused epilogue ----
    const int col = lane & 15, rq = lane >> 4;
    if (khalf == 1) {
#pragma unroll
      for (int reg = 0; reg < 4; ++reg)
#pragma unroll
        for (int ct = 0; ct < 8; ++ct)
          Red[strip][rq * 4 + reg][ct * 16 + col] = acc[ct][reg];
    }
    __syncthreads();
    if (khalf == 0) {
      const float* xr = xwsr + ((size_t)b * NN + rowb) * FD;
      float* ob = out + ((size_t)b * NN + rowb) * FD;
#pragma unroll
      for (int reg = 0; reg < 4; ++reg) {
        const int rloc = rq * 4 + reg;
        const float rn = r[b * NN + rowb + rloc];
#pragma unroll
        for (int ct = 0; ct < 8; ++ct) {
          const int o = ct * 16 + col;
          float v = acc[ct][reg] + Red[strip][rloc][o] + xr[(size_t)rloc * FD + o];
          v = rn * v + bias[o];
          ob[(size_t)rloc * FD + o] = v > 0.f ? v : 0.01f * v;
        }
      }
    }
    __syncthreads();  // protect Red across reps
    asm volatile("" ::: "memory");
  }
}

extern "C" void kernel_launch(void* const* d_in, const int* in_sizes, int n_in,
                              void* d_out, int out_size, void* d_ws, size_t ws_size,
                              hipStream_t stream) {
  (void)in_sizes; (void)n_in; (void)out_size; (void)ws_size;
  const float* X    = (const float*)d_in[0];
  const float* adj  = (const float*)d_in[1];
  const float* W    = (const float*)d_in[2];
  const float* bias = (const float*)d_in[3];
  float* out = (float*)d_out;

  char* ws = (char*)d_ws;
  float* r     = (float*)ws;                       // 64 KB
  short* bpack = (short*)(ws + 65536);             // 4 MB
  float* xwsr  = (float*)(ws + 4259840);           // 8 MB

  k_degree_x4<<<dim3(BB * NN / 4), dim3(256), 0, stream>>>(adj, r);
  k_xw<<<dim3(NN / 64, BB), dim3(256), 0, stream>>>(X, W, r, bpack, xwsr);
  k_gemm2_x3<<<dim3(NN / 32, BB), dim3(256), 0, stream>>>(adj, bpack, xwsr, r, bias, out);
}

// Round 7
// 114.877 us; speedup vs baseline: 5.5246x; 5.5246x over previous
//
#include <hip/hip_runtime.h>
#include <hip/hip_bf16.h>

#define BB 8
#define NN 2048
#define FD 128

typedef float f32x4 __attribute__((ext_vector_type(4)));
typedef short bf16x8 __attribute__((ext_vector_type(8)));
typedef short s16x4 __attribute__((ext_vector_type(4)));

__device__ __forceinline__ short f2bf(float f) {
  union { __hip_bfloat16 h; short s; } u;
  u.h = __float2bfloat16(f);
  return u.s;
}

// ---------------- kernel 1: r = rsqrt(1 + rowsum(adj)) ----------------
// Pure 134 MB streaming read at full occupancy.
__global__ __launch_bounds__(256) void k_degree(const float* __restrict__ adj,
                                                float* __restrict__ r) {
  const int row  = blockIdx.x * 4 + (threadIdx.x >> 6);
  const int lane = threadIdx.x & 63;
  const f32x4* p = reinterpret_cast<const f32x4*>(adj + (size_t)row * NN);
  float s = 0.f;
#pragma unroll
  for (int i = 0; i < 8; ++i) {
    f32x4 v = p[lane + 64 * i];
    s += (v.x + v.y) + (v.z + v.w);
  }
#pragma unroll
  for (int off = 32; off >= 1; off >>= 1) s += __shfl_xor(s, off, 64);
  if (lane == 0) r[row] = rsqrtf(1.0f + s);
}

// ---------------- kernel 2: XWs = r[m] * (X @ W), pack B-fragments ----------
// bpack: elem (m,o) -> (m>>3)*1024 + o*8 + (m&7); xwsr fp32 row-major.
__global__ __launch_bounds__(256) void k_xw(const float* __restrict__ X,
                                            const float* __restrict__ W,
                                            const float* __restrict__ r,
                                            short* __restrict__ bpack,
                                            float* __restrict__ xwsr) {
  __shared__ __align__(16) float Xs[64][132];
  __shared__ __align__(16) float Ws[128][128];
  const int b  = blockIdx.y;
  const int m0 = blockIdx.x * 64;
  const int t  = threadIdx.x;
  {
    const f32x4* wp = reinterpret_cast<const f32x4*>(W);
    f32x4* wd = reinterpret_cast<f32x4*>(&Ws[0][0]);
#pragma unroll
    for (int i = 0; i < 16; ++i) wd[t + 256 * i] = wp[t + 256 * i];
    const f32x4* xp = reinterpret_cast<const f32x4*>(X + ((size_t)b * NN + m0) * FD);
#pragma unroll
    for (int i = 0; i < 8; ++i) {
      int slot = t + 256 * i;
      f32x4 v = xp[slot];
      *reinterpret_cast<f32x4*>(&Xs[slot >> 5][(slot & 31) * 4]) = v;
    }
  }
  __syncthreads();
  const int ot = (t & 15) * 8;
  const int mt = (t >> 4) * 4;
  float acc[4][8];
#pragma unroll
  for (int i = 0; i < 4; ++i)
#pragma unroll
    for (int j = 0; j < 8; ++j) acc[i][j] = 0.f;

  for (int k = 0; k < 128; k += 4) {
    f32x4 xv[4];
#pragma unroll
    for (int i = 0; i < 4; ++i) xv[i] = *reinterpret_cast<const f32x4*>(&Xs[mt + i][k]);
#pragma unroll
    for (int kk = 0; kk < 4; ++kk) {
      float wv[8];
#pragma unroll
      for (int j = 0; j < 8; ++j) wv[j] = Ws[k + kk][ot + j];
#pragma unroll
      for (int i = 0; i < 4; ++i)
#pragma unroll
        for (int j = 0; j < 8; ++j) acc[i][j] = fmaf(xv[i][kk], wv[j], acc[i][j]);
    }
  }
  const int bm = b * NN + m0 + mt;
#pragma unroll
  for (int i = 0; i < 4; ++i) {
    float rm = r[bm + i];
#pragma unroll
    for (int j = 0; j < 8; ++j) acc[i][j] *= rm;
  }
#pragma unroll
  for (int i = 0; i < 4; ++i) {
    f32x4 lo = {acc[i][0], acc[i][1], acc[i][2], acc[i][3]};
    f32x4 hi = {acc[i][4], acc[i][5], acc[i][6], acc[i][7]};
    float* dst = xwsr + (size_t)(bm + i) * FD + ot;
    *reinterpret_cast<f32x4*>(dst) = lo;
    *reinterpret_cast<f32x4*>(dst + 4) = hi;
  }
  short* bp = bpack + (size_t)b * NN * FD;
  const int grp = (m0 + mt) >> 3;
  const int h   = ((m0 + mt) >> 2) & 1;
#pragma unroll
  for (int j = 0; j < 8; ++j) {
    s16x4 sv;
#pragma unroll
    for (int i = 0; i < 4; ++i) sv[i] = f2bf(acc[i][j]);
    *reinterpret_cast<s16x4*>(bp + (size_t)grp * 1024 + (ot + j) * 8 + h * 4) = sv;
  }
}

// ---------------- kernel 3: low-pressure LDS-free MFMA GEMM -----------------
// out = leaky(r[n] * ((adj @ XWs) + XWs[n]) + bias)
// Block = 4 waves over 16 rows x 128 cols; wave w owns cols [w*32, w*32+32),
// full K. All waves share the same A rows (L1/L2 dedup). acc 8 + A 4-deep 32
// + B 4-deep 32 VGPRs => ~90, capped at 128 via launch_bounds -> 4 waves/SIMD.
__global__ __launch_bounds__(256, 4) void k_gemm4(const float* __restrict__ adj,
                                                  const short* __restrict__ bpack,
                                                  const float* __restrict__ xwsr,
                                                  const float* __restrict__ r,
                                                  const float* __restrict__ bias,
                                                  float* __restrict__ out) {
  const int b    = blockIdx.y;
  const int n0   = blockIdx.x * 16;
  const int t    = threadIdx.x;
  const int lane = t & 63;
  const int w    = t >> 6;

  const float* ap  = adj + ((size_t)b * NN + n0 + (lane & 15)) * NN + (lane >> 4) * 8;
  const short* bpb = bpack + (size_t)b * NN * FD + (size_t)(lane >> 4) * 1024
                   + (w * 32 + (lane & 15)) * 8;

  f32x4 acc[2];
  acc[0] = (f32x4){0.f, 0.f, 0.f, 0.f};
  acc[1] = (f32x4){0.f, 0.f, 0.f, 0.f};

  f32x4  aS[4][2];
  bf16x8 bS[4][2];

  auto loadA = [&](int ks, f32x4 (&d)[2]) {
    const f32x4* q = reinterpret_cast<const f32x4*>(ap + ks * 32);
    d[0] = q[0];
    d[1] = q[1];
  };
  auto loadB = [&](int ks, bf16x8 (&d)[2]) {
    const short* p = bpb + (size_t)ks * 4096;
    d[0] = *reinterpret_cast<const bf16x8*>(p);
    d[1] = *reinterpret_cast<const bf16x8*>(p + 128);
  };
  auto step = [&](f32x4 (&sa)[2], bf16x8 (&sb)[2]) {
    bf16x8 af;
#pragma unroll
    for (int i = 0; i < 4; ++i) { af[i] = f2bf(sa[0][i]); af[4 + i] = f2bf(sa[1][i]); }
    acc[0] = __builtin_amdgcn_mfma_f32_16x16x32_bf16(af, sb[0], acc[0], 0, 0, 0);
    acc[1] = __builtin_amdgcn_mfma_f32_16x16x32_bf16(af, sb[1], acc[1], 0, 0, 0);
  };

#pragma unroll
  for (int i = 0; i < 4; ++i) { loadA(i, aS[i]); loadB(i, bS[i]); }
#pragma unroll 4
  for (int ks = 0; ks < 60; ++ks) {
    step(aS[ks & 3], bS[ks & 3]);
    loadA(ks + 4, aS[ks & 3]);
    loadB(ks + 4, bS[ks & 3]);
  }
#pragma unroll
  for (int ks = 60; ks < 64; ++ks) step(aS[ks & 3], bS[ks & 3]);

  // epilogue: C/D layout col = lane&15, row = (lane>>4)*4 + reg
  const int col = lane & 15, rq = lane >> 4;
  const float* xr = xwsr + ((size_t)b * NN + n0) * FD;
  float* ob = out + ((size_t)b * NN + n0) * FD;
#pragma unroll
  for (int reg = 0; reg < 4; ++reg) {
    const int rloc = rq * 4 + reg;
    const float rn = r[b * NN + n0 + rloc];
#pragma unroll
    for (int ct = 0; ct < 2; ++ct) {
      const int o = w * 32 + ct * 16 + col;
      float v = acc[ct][reg] + xr[(size_t)rloc * FD + o];
      v = rn * v + bias[o];
      ob[(size_t)rloc * FD + o] = v > 0.f ? v : 0.01f * v;
    }
  }
}

extern "C" void kernel_launch(void* const* d_in, const int* in_sizes, int n_in,
                              void* d_out, int out_size, void* d_ws, size_t ws_size,
                              hipStream_t stream) {
  (void)in_sizes; (void)n_in; (void)out_size; (void)ws_size;
  const float* X    = (const float*)d_in[0];
  const float* adj  = (const float*)d_in[1];
  const float* W    = (const float*)d_in[2];
  const float* bias = (const float*)d_in[3];
  float* out = (float*)d_out;

  char* ws = (char*)d_ws;
  float* r     = (float*)ws;                       // 64 KB
  short* bpack = (short*)(ws + 65536);             // 4 MB
  float* xwsr  = (float*)(ws + 4259840);           // 8 MB

  k_degree<<<dim3(BB * NN / 4), dim3(256), 0, stream>>>(adj, r);
  k_xw<<<dim3(NN / 64, BB), dim3(256), 0, stream>>>(X, W, r, bpack, xwsr);
  k_gemm4<<<dim3(NN / 16, BB), dim3(256), 0, stream>>>(adj, bpack, xwsr, r, bias, out);
}

// Round 8
// 73.988 us; speedup vs baseline: 8.5777x; 1.5526x over previous
//
#include <hip/hip_runtime.h>
#include <hip/hip_bf16.h>

#define BB 8
#define NN 2048
#define FD 128

typedef float f32x4 __attribute__((ext_vector_type(4)));
typedef short bf16x8 __attribute__((ext_vector_type(8)));
typedef short s16x4 __attribute__((ext_vector_type(4)));

__device__ __forceinline__ short f2bf(float f) {
  union { __hip_bfloat16 h; short s; } u;
  u.h = __float2bfloat16(f);
  return u.s;
}

// ---------------- kernel 1: r = rsqrt(1 + rowsum(adj)) ----------------
__global__ __launch_bounds__(256) void k_degree(const float* __restrict__ adj,
                                                float* __restrict__ r) {
  const int row  = blockIdx.x * 4 + (threadIdx.x >> 6);
  const int lane = threadIdx.x & 63;
  const f32x4* p = reinterpret_cast<const f32x4*>(adj + (size_t)row * NN);
  float s = 0.f;
#pragma unroll
  for (int i = 0; i < 8; ++i) {
    f32x4 v = p[lane + 64 * i];
    s += (v.x + v.y) + (v.z + v.w);
  }
#pragma unroll
  for (int off = 32; off >= 1; off >>= 1) s += __shfl_xor(s, off, 64);
  if (lane == 0) r[row] = rsqrtf(1.0f + s);
}

// ---------------- kernel 2: XWs = r[m] * (X @ W), pack B-fragments ----------
// bpack: elem (m,o) -> (m>>3)*1024 + o*8 + (m&7); xwsr fp32 row-major.
__global__ __launch_bounds__(256) void k_xw(const float* __restrict__ X,
                                            const float* __restrict__ W,
                                            const float* __restrict__ r,
                                            short* __restrict__ bpack,
                                            float* __restrict__ xwsr) {
  __shared__ __align__(16) float Xs[64][132];
  __shared__ __align__(16) float Ws[128][128];
  const int b  = blockIdx.y;
  const int m0 = blockIdx.x * 64;
  const int t  = threadIdx.x;
  {
    const f32x4* wp = reinterpret_cast<const f32x4*>(W);
    f32x4* wd = reinterpret_cast<f32x4*>(&Ws[0][0]);
#pragma unroll
    for (int i = 0; i < 16; ++i) wd[t + 256 * i] = wp[t + 256 * i];
    const f32x4* xp = reinterpret_cast<const f32x4*>(X + ((size_t)b * NN + m0) * FD);
#pragma unroll
    for (int i = 0; i < 8; ++i) {
      int slot = t + 256 * i;
      f32x4 v = xp[slot];
      *reinterpret_cast<f32x4*>(&Xs[slot >> 5][(slot & 31) * 4]) = v;
    }
  }
  __syncthreads();
  const int ot = (t & 15) * 8;
  const int mt = (t >> 4) * 4;
  float acc[4][8];
#pragma unroll
  for (int i = 0; i < 4; ++i)
#pragma unroll
    for (int j = 0; j < 8; ++j) acc[i][j] = 0.f;

  for (int k = 0; k < 128; k += 4) {
    f32x4 xv[4];
#pragma unroll
    for (int i = 0; i < 4; ++i) xv[i] = *reinterpret_cast<const f32x4*>(&Xs[mt + i][k]);
#pragma unroll
    for (int kk = 0; kk < 4; ++kk) {
      float wv[8];
#pragma unroll
      for (int j = 0; j < 8; ++j) wv[j] = Ws[k + kk][ot + j];
#pragma unroll
      for (int i = 0; i < 4; ++i)
#pragma unroll
        for (int j = 0; j < 8; ++j) acc[i][j] = fmaf(xv[i][kk], wv[j], acc[i][j]);
    }
  }
  const int bm = b * NN + m0 + mt;
#pragma unroll
  for (int i = 0; i < 4; ++i) {
    float rm = r[bm + i];
#pragma unroll
    for (int j = 0; j < 8; ++j) acc[i][j] *= rm;
  }
#pragma unroll
  for (int i = 0; i < 4; ++i) {
    f32x4 lo = {acc[i][0], acc[i][1], acc[i][2], acc[i][3]};
    f32x4 hi = {acc[i][4], acc[i][5], acc[i][6], acc[i][7]};
    float* dst = xwsr + (size_t)(bm + i) * FD + ot;
    *reinterpret_cast<f32x4*>(dst) = lo;
    *reinterpret_cast<f32x4*>(dst + 4) = hi;
  }
  short* bp = bpack + (size_t)b * NN * FD;
  const int grp = (m0 + mt) >> 3;
  const int h   = ((m0 + mt) >> 2) & 1;
#pragma unroll
  for (int j = 0; j < 8; ++j) {
    s16x4 sv;
#pragma unroll
    for (int i = 0; i < 4; ++i) sv[i] = f2bf(acc[i][j]);
    *reinterpret_cast<s16x4*>(bp + (size_t)grp * 1024 + (ot + j) * 8 + h * 4) = sv;
  }
}

// ---------------- kernel 3: 2-phase LDS-staged MFMA GEMM --------------------
// out = leaky(r[n] * ((adj @ XWs) + XWs[n]) + bias)
// BM=16 x BN=128 x BK=128; grid 1024 = 4 blocks/CU. A: global fp32 -> reg ->
// cvt bf16 -> swizzled LDS [16][128] (byte ^= (row&7)<<4, m214 recipe), double
// buffered. B: bpack frags in named even/odd register slots (full unroll ->
// static indices). Wave w owns cols [w*32, w*32+32). 8 MFMA/tile/wave.
#define NT 16  // K tiles of 128
__global__ __launch_bounds__(256, 4) void k_gemm5(const float* __restrict__ adj,
                                                  const short* __restrict__ bpack,
                                                  const float* __restrict__ xwsr,
                                                  const float* __restrict__ r,
                                                  const float* __restrict__ bias,
                                                  float* __restrict__ out) {
  __shared__ __align__(16) short As[2][16 * 128];  // 4 KB each, swizzled bf16
  const int b    = blockIdx.y;
  const int n0   = blockIdx.x * 16;
  const int t    = threadIdx.x;
  const int lane = t & 63;
  const int w    = t >> 6;

  // staging role: thread t stages row sr, 8-elem unit su (16B bf16 after cvt)
  const int sr = t >> 4;
  const int su = t & 15;
  const float* gsrc = adj + ((size_t)b * NN + n0 + sr) * NN + su * 8;
  const int wofs = sr * 256 + ((su ^ (sr & 7)) << 4);

  // compute role
  const int fr = lane & 15;   // fragment row / output col-within-frag
  const int kg = lane >> 4;   // k-group
  const short* bpb = bpack + (size_t)b * NN * FD + (size_t)kg * 1024 + (w * 32 + fr) * 8;

  f32x4 acc[2];
  acc[0] = (f32x4){0.f, 0.f, 0.f, 0.f};
  acc[1] = (f32x4){0.f, 0.f, 0.f, 0.f};

  f32x4 ga[2];              // staged raw fp32 (32 B)
  bf16x8 Bev[4][2], Bod[4][2];  // named even/odd B slots

  auto issueA = [&](int kt) {
    const f32x4* p = reinterpret_cast<const f32x4*>(gsrc + (size_t)kt * 128);
    ga[0] = p[0];
    ga[1] = p[1];
  };
  auto issueB = [&](int kt, bf16x8 (&d)[4][2]) {
    const short* bt = bpb + (size_t)kt * 16 * 1024;
#pragma unroll
    for (int kf = 0; kf < 4; ++kf)
#pragma unroll
      for (int cf = 0; cf < 2; ++cf)
        d[kf][cf] = *reinterpret_cast<const bf16x8*>(bt + (size_t)kf * 4096 + cf * 128);
  };
  auto commitA = [&](int buf) {
    bf16x8 o;
#pragma unroll
    for (int i = 0; i < 4; ++i) { o[i] = f2bf(ga[0][i]); o[4 + i] = f2bf(ga[1][i]); }
    *reinterpret_cast<bf16x8*>(reinterpret_cast<char*>(&As[buf][0]) + wofs) = o;
  };
  auto compute = [&](int buf, bf16x8 (&bs)[4][2]) {
    const char* abase = reinterpret_cast<const char*>(&As[buf][0]);
#pragma unroll
    for (int kf = 0; kf < 4; ++kf) {
      bf16x8 af = *reinterpret_cast<const bf16x8*>(
          abase + fr * 256 + (((kf * 4 + kg) ^ (fr & 7)) << 4));
      acc[0] = __builtin_amdgcn_mfma_f32_16x16x32_bf16(af, bs[kf][0], acc[0], 0, 0, 0);
      acc[1] = __builtin_amdgcn_mfma_f32_16x16x32_bf16(af, bs[kf][1], acc[1], 0, 0, 0);
    }
  };

  // prologue: tile 0 into LDS buf0 and B even slot
  issueA(0);
  issueB(0, Bev);
  commitA(0);
  __syncthreads();

#pragma unroll
  for (int kt = 0; kt < NT; ++kt) {
    const int cur = kt & 1;
    if (kt + 1 < NT) issueA(kt + 1);
    if (kt + 1 < NT) {
      if (cur) issueB(kt + 1, Bev); else issueB(kt + 1, Bod);
    }
    if (cur) compute(1, Bod); else compute(0, Bev);
    if (kt + 1 < NT) commitA(cur ^ 1);
    __syncthreads();
  }

  // epilogue: C/D layout col = lane&15, row = (lane>>4)*4 + reg
  const int col = lane & 15, rq = lane >> 4;
  const float* xr = xwsr + ((size_t)b * NN + n0) * FD;
  float* ob = out + ((size_t)b * NN + n0) * FD;
#pragma unroll
  for (int reg = 0; reg < 4; ++reg) {
    const int rloc = rq * 4 + reg;
    const float rn = r[b * NN + n0 + rloc];
#pragma unroll
    for (int cf = 0; cf < 2; ++cf) {
      const int o = w * 32 + cf * 16 + col;
      float v = acc[cf][reg] + xr[(size_t)rloc * FD + o];
      v = rn * v + bias[o];
      ob[(size_t)rloc * FD + o] = v > 0.f ? v : 0.01f * v;
    }
  }
}

extern "C" void kernel_launch(void* const* d_in, const int* in_sizes, int n_in,
                              void* d_out, int out_size, void* d_ws, size_t ws_size,
                              hipStream_t stream) {
  (void)in_sizes; (void)n_in; (void)out_size; (void)ws_size;
  const float* X    = (const float*)d_in[0];
  const float* adj  = (const float*)d_in[1];
  const float* W    = (const float*)d_in[2];
  const float* bias = (const float*)d_in[3];
  float* out = (float*)d_out;

  char* ws = (char*)d_ws;
  float* r     = (float*)ws;                       // 64 KB
  short* bpack = (short*)(ws + 65536);             // 4 MB
  float* xwsr  = (float*)(ws + 4259840);           // 8 MB

  k_degree<<<dim3(BB * NN / 4), dim3(256), 0, stream>>>(adj, r);
  k_xw<<<dim3(NN / 64, BB), dim3(256), 0, stream>>>(X, W, r, bpack, xwsr);
  k_gemm5<<<dim3(NN / 16, BB), dim3(256), 0, stream>>>(adj, bpack, xwsr, r, bias, out);
}